// Round 18
// baseline (5550.944 us; speedup 1.0000x reference)
//
#include <hip/hip_runtime.h>

#define B_TOTAL 16384
#define INPUT   512
#define HID     128
#define OUTW    64
#define STEPS   10
#define GATES   512
#define RPB     32    // rows per block
#define TPB     512
#define HXP     132   // hxhi row stride (shorts) -> 264B rows, conflict-free out reads
#define KCH     32    // k-chunk (64 KB) staged in LDS, double-buffered
#define CHUNK_V4 (KCH*HID)  // 4096 float4 per chunk

typedef float f32x4  __attribute__((ext_vector_type(4)));
typedef short short8 __attribute__((ext_vector_type(8)));

__device__ __forceinline__ unsigned short f2bf(float f) {
    unsigned u = __builtin_bit_cast(unsigned, f);
    u += 0x7FFFu + ((u >> 16) & 1u);          // RNE
    return (unsigned short)(u >> 16);
}
__device__ __forceinline__ float bf2f(unsigned short h) {
    unsigned u = ((unsigned)h) << 16;
    return __builtin_bit_cast(float, u);
}

// ws layout (proven budget):
//   floats: W_effP [0,65536)   (W_hh + W_ih@W_out, packed [k][h][gate])
//           W_hhP  [65536,131072)
//           b_all  [131072,131584)   b2 [131584,132096)
//   ushorts from (ws+132096): WoutHi [0,8192)  WoutLo [8192,16384)

__global__ __launch_bounds__(128) void precompute_kernel(
    const float* __restrict__ W_ih, const float* __restrict__ W_hh,
    const float* __restrict__ b_ih, const float* __restrict__ b_hh,
    const float* __restrict__ W_out, const float* __restrict__ b_out,
    float* __restrict__ ws)
{
    const int j = blockIdx.x;   // 0..511: gate row
    const int k = threadIdx.x;  // 0..127
    float* W_effP = ws;
    float* W_hhP  = ws + 65536;
    float* b_all  = ws + 131072;
    float* b2     = ws + 131584;
    unsigned short* WoutHi = (unsigned short*)(ws + 132096);
    unsigned short* WoutLo = WoutHi + 8192;

    const int g  = j >> 7;
    const int jj = j & 127;

    float whh = W_hh[j*HID + k];
    float weff = whh;
    for (int m = 0; m < OUTW; ++m)
        weff += W_ih[j*OUTW + m] * W_out[m*HID + k];
    W_effP[(k*HID + jj)*4 + g] = weff;    // [k][h][gate]
    W_hhP [(k*HID + jj)*4 + g] = whh;

    if (j < OUTW) {
        float wo = W_out[j*HID + k];
        const int oidx = (((k>>5)*OUTW + j) << 5) + (((k>>3)&3) << 3) + (k&7);
        unsigned short ho = f2bf(wo);
        WoutHi[oidx] = ho; WoutLo[oidx] = f2bf(wo - bf2f(ho));
    }
    if (k == 0) {
        float s = 0.f;
        for (int m = 0; m < OUTW; ++m) s += W_ih[j*OUTW + m] * b_out[m];
        float bb = b_ih[j] + b_hh[j];
        b_all[j] = bb + s;
        b2[j]    = bb;
    }
}

__device__ __forceinline__ float fast_sigmoid(float x) {
    return 1.f / (1.f + __builtin_amdgcn_exp2f(-1.4426950408889634f * x));
}
__device__ __forceinline__ float fast_tanh(float x) {
    return 1.f - 2.f / (1.f + __builtin_amdgcn_exp2f(2.8853900817779268f * x));
}

#define MFMA16(A,B,C) __builtin_amdgcn_mfma_f32_16x16x32_bf16((A),(B),(C),0,0,0)

// direct global->LDS stage of one 64 KB chunk (8 x 16B per thread, no VGPRs)
__device__ __forceinline__ void stage_chunk(const f32x4* src, f32x4* dst, int tid) {
    #pragma unroll
    for (int i = 0; i < 8; ++i)
        __builtin_amdgcn_global_load_lds(
            (const __attribute__((address_space(1))) void*)(src + i*TPB + tid),
            (__attribute__((address_space(3))) void*)(dst + i*TPB + tid), 16, 0, 0);
}

__global__ __launch_bounds__(TPB, 2) void lstm_kernel(
    const float* __restrict__ x, const float* __restrict__ ws,
    const float* __restrict__ W_init, const float* __restrict__ b_init,
    const float* __restrict__ b_out, float* __restrict__ out)
{
    __shared__ f32x4          wbuf[2][CHUNK_V4];  // 128 KB staged weights
    __shared__ float          hxs [RPB][HID];     // 16 KB fp32 state
    __shared__ unsigned short hxhi[RPB][HXP];     // 8.25 KB bf16-hi (out-MFMA A)

    const f32x4* W_effP4 = (const f32x4*)(ws);
    const f32x4* W_hhP4  = (const f32x4*)(ws + 65536);
    const float* b_all   = ws + 131072;
    const float* b2      = ws + 131584;
    const unsigned short* WoutHi = (const unsigned short*)(ws + 132096);
    const unsigned short* WoutLo = WoutHi + 8192;

    const int tid = threadIdx.x;
    const int h   = tid & 127;     // owned hidden/gate column
    const int rq  = tid >> 7;      // 0..3 -> row group of 8
    const int b0  = blockIdx.x * RPB;

    // stage chunk 0 of W_hh while init runs
    stage_chunk(W_hhP4, wbuf[0], tid);

    // ---- init GEMM (fp32): hx0 = x @ W_init^T + b_init (chain = R9/R14) ----
    float cx[8];
    {
        float acc[8];
        const float bi = b_init[h];
        #pragma unroll
        for (int r = 0; r < 8; ++r) acc[r] = bi;
        for (int k0 = 0; k0 < INPUT; k0 += 4) {
            f32x4 wv = *(const f32x4*)&W_init[h*INPUT + k0];
            #pragma unroll
            for (int r = 0; r < 8; ++r) {
                const f32x4* xp = (const f32x4*)&x[(size_t)(b0 + rq*8 + r)*INPUT + k0];
                f32x4 xv = __builtin_nontemporal_load(xp);
                acc[r] = fmaf(xv.x, wv.x, acc[r]);
                acc[r] = fmaf(xv.y, wv.y, acc[r]);
                acc[r] = fmaf(xv.z, wv.z, acc[r]);
                acc[r] = fmaf(xv.w, wv.w, acc[r]);
            }
        }
        #pragma unroll
        for (int r = 0; r < 8; ++r) {
            int row = rq*8 + r;
            float v = acc[r];
            cx[r] = v;
            hxs[row][h] = v;
            hxhi[row][h] = f2bf(v);
        }
    }
    asm volatile("s_waitcnt vmcnt(0)" ::: "memory");
    __syncthreads();   // init state + chunk 0 staged & visible

    // ---- out-MFMA wave mapping (8 waves: 2 row tiles x 4 col tiles) ----
    const int w  = tid >> 6;        // wave 0..7
    const int l  = tid & 63;
    const int i  = l & 15;
    const int q  = l >> 4;
    const int pm = w & 1;           // row tile
    const int jo = (w >> 1)*16 + i; // out column
    const float boutj = b_out[jo];

    for (int t = 0; t < STEPS; ++t) {
        const f32x4* Wt = t ? W_effP4 : W_hhP4;
        const float* bb = t ? b_all   : b2;

        // ---- gates GEMM (fp32 VALU, chain identical to R9/R14; weights from
        //      LDS chunks, double-buffered, stage overlapped with compute) ----
        float aI[8], aF[8], aG[8], aO[8];
        {
            const float bIv = bb[h], bFv = bb[128+h], bGv = bb[256+h], bOv = bb[384+h];
            #pragma unroll
            for (int r = 0; r < 8; ++r) { aI[r]=bIv; aF[r]=bFv; aG[r]=bGv; aO[r]=bOv; }
        }
        #pragma unroll
        for (int c = 0; c < 4; ++c) {
            // issue next chunk's stage into the other buffer (overlaps compute)
            if (t*4 + c < STEPS*4 - 1) {
                const f32x4* np = (c == 3) ? W_effP4 : Wt;
                const int nc = (c + 1) & 3;
                stage_chunk(np + nc*CHUNK_V4, wbuf[(c+1)&1], tid);
            }
            // compute chunk c (k = c*32 .. c*32+31)
            const f32x4* wc = wbuf[c&1];
            const int kbase = c * KCH;
            #pragma unroll
            for (int kk = 0; kk < KCH; kk += 4) {
                f32x4 w0 = wc[(kk+0)*HID + h];
                f32x4 w1 = wc[(kk+1)*HID + h];
                f32x4 w2 = wc[(kk+2)*HID + h];
                f32x4 w3 = wc[(kk+3)*HID + h];
                #pragma unroll
                for (int r = 0; r < 8; ++r) {
                    float4 hv = *(const float4*)&hxs[rq*8 + r][kbase + kk];
                    aI[r] = fmaf(hv.x, w0.x, aI[r]); aF[r] = fmaf(hv.x, w0.y, aF[r]);
                    aG[r] = fmaf(hv.x, w0.z, aG[r]); aO[r] = fmaf(hv.x, w0.w, aO[r]);
                    aI[r] = fmaf(hv.y, w1.x, aI[r]); aF[r] = fmaf(hv.y, w1.y, aF[r]);
                    aG[r] = fmaf(hv.y, w1.z, aG[r]); aO[r] = fmaf(hv.y, w1.w, aO[r]);
                    aI[r] = fmaf(hv.z, w2.x, aI[r]); aF[r] = fmaf(hv.z, w2.y, aF[r]);
                    aG[r] = fmaf(hv.z, w2.z, aG[r]); aO[r] = fmaf(hv.z, w2.w, aO[r]);
                    aI[r] = fmaf(hv.w, w3.x, aI[r]); aF[r] = fmaf(hv.w, w3.y, aF[r]);
                    aG[r] = fmaf(hv.w, w3.z, aG[r]); aO[r] = fmaf(hv.w, w3.w, aO[r]);
                }
            }
            asm volatile("s_waitcnt vmcnt(0)" ::: "memory");  // next stage landed
            __syncthreads();   // all waves done with chunk c; next chunk visible
        }

        // ---- cell update (fp32, in-register cx; chain identical) ----
        #pragma unroll
        for (int r = 0; r < 8; ++r) {
            float ig = fast_sigmoid(aI[r]);
            float fg = fast_sigmoid(aF[r]);
            float gg = fast_tanh(aG[r]);
            float og = fast_sigmoid(aO[r]);
            float c  = fmaf(fg, cx[r], ig * gg);
            cx[r] = c;
            float hv = og * fast_tanh(c);
            int row = rq*8 + r;
            hxs[row][h] = hv;
            hxhi[row][h] = f2bf(hv);
        }
        __syncthreads();   // new hx visible

        // ---- out GEMM via MFMA: A = bf16-hi(hx), B = Wout hi+lo (2-pass) ----
        // A-lo dropped: unamplified out-only error ~1e-4, within margin.
        {
            f32x4 oa = {boutj, boutj, boutj, boutj};
            #pragma unroll
            for (int kc = 0; kc < 4; ++kc) {
                short8 Ah = *(const short8*)&hxhi[pm*16 + i][kc*32 + 8*q];
                int oidx = ((kc*OUTW + jo) << 5) + (q << 3);
                short8 Bh = *(const short8*)&WoutHi[oidx];
                short8 Bl = *(const short8*)&WoutLo[oidx];
                oa = MFMA16(Ah, Bh, oa);
                oa = MFMA16(Ah, Bl, oa);
            }
            #pragma unroll
            for (int r = 0; r < 4; ++r) {
                int row = pm*16 + 4*q + r;
                __builtin_nontemporal_store(oa[r],
                    &out[(size_t)(b0 + row)*(STEPS*OUTW) + t*OUTW + jo]);
            }
        }
        // no trailing barrier: next stage targets wbuf guarded by chunk-3 barrier;
        // out reads hxhi guarded by the cell barrier.
    }
}

extern "C" void kernel_launch(void* const* d_in, const int* in_sizes, int n_in,
                              void* d_out, int out_size, void* d_ws, size_t ws_size,
                              hipStream_t stream)
{
    const float* x      = (const float*)d_in[0];
    const float* W_ih   = (const float*)d_in[1];
    const float* W_hh   = (const float*)d_in[2];
    const float* b_ih   = (const float*)d_in[3];
    const float* b_hh   = (const float*)d_in[4];
    const float* W_init = (const float*)d_in[5];
    const float* b_init = (const float*)d_in[6];
    const float* W_out  = (const float*)d_in[7];
    const float* b_out  = (const float*)d_in[8];
    float* out = (float*)d_out;
    float* ws  = (float*)d_ws;

    precompute_kernel<<<GATES, HID, 0, stream>>>(W_ih, W_hh, b_ih, b_hh, W_out, b_out, ws);
    lstm_kernel<<<B_TOTAL/RPB, TPB, 0, stream>>>(x, ws, W_init, b_init, b_out, out);
}

// Round 19
// 490.894 us; speedup vs baseline: 11.3078x; 11.3078x over previous
//
#include <hip/hip_runtime.h>

#define B_TOTAL 16384
#define INPUT   512
#define HID     128
#define OUTW    64
#define STEPS   10
#define GATES   512
#define RPB     16    // rows per block
#define TPB     256
#define HXP2    136   // bf16 mirror row stride (shorts)

typedef float f32x4  __attribute__((ext_vector_type(4)));
typedef float f32x2  __attribute__((ext_vector_type(2)));
typedef short short8 __attribute__((ext_vector_type(8)));

__device__ __forceinline__ unsigned short f2bf(float f) {
    unsigned u = __builtin_bit_cast(unsigned, f);
    u += 0x7FFFu + ((u >> 16) & 1u);          // RNE
    return (unsigned short)(u >> 16);
}
__device__ __forceinline__ float bf2f(unsigned short h) {
    unsigned u = ((unsigned)h) << 16;
    return __builtin_bit_cast(float, u);
}

// ws layout:
//   floats: W_effP [0,65536)   (W_hh + W_ih@W_out, packed [k][h][gate])
//           W_hhP  [65536,131072)
//           b_all  [131072,131584)   b2 [131584,132096)
//   ushorts from (ws+132096): WoutHi [0,8192)  WoutLo [8192,16384)

__global__ __launch_bounds__(128) void precompute_kernel(
    const float* __restrict__ W_ih, const float* __restrict__ W_hh,
    const float* __restrict__ b_ih, const float* __restrict__ b_hh,
    const float* __restrict__ W_out, const float* __restrict__ b_out,
    float* __restrict__ ws)
{
    const int j = blockIdx.x;   // 0..511: gate row
    const int k = threadIdx.x;  // 0..127
    float* W_effP = ws;
    float* W_hhP  = ws + 65536;
    float* b_all  = ws + 131072;
    float* b2     = ws + 131584;
    unsigned short* WoutHi = (unsigned short*)(ws + 132096);
    unsigned short* WoutLo = WoutHi + 8192;

    const int g  = j >> 7;
    const int jj = j & 127;

    float whh = W_hh[j*HID + k];
    float weff = whh;
    for (int m = 0; m < OUTW; ++m)
        weff += W_ih[j*OUTW + m] * W_out[m*HID + k];
    W_effP[(k*HID + jj)*4 + g] = weff;    // [k][h][gate]
    W_hhP [(k*HID + jj)*4 + g] = whh;

    if (j < OUTW) {
        float wo = W_out[j*HID + k];
        const int oidx = (((k>>5)*OUTW + j) << 5) + (((k>>3)&3) << 3) + (k&7);
        unsigned short ho = f2bf(wo);
        WoutHi[oidx] = ho; WoutLo[oidx] = f2bf(wo - bf2f(ho));
    }
    if (k == 0) {
        float s = 0.f;
        for (int m = 0; m < OUTW; ++m) s += W_ih[j*OUTW + m] * b_out[m];
        float bb = b_ih[j] + b_hh[j];
        b_all[j] = bb + s;
        b2[j]    = bb;
    }
}

__device__ __forceinline__ float fast_sigmoid(float x) {
    return 1.f / (1.f + __builtin_amdgcn_exp2f(-1.4426950408889634f * x));
}
__device__ __forceinline__ float fast_tanh(float x) {
    return 1.f - 2.f / (1.f + __builtin_amdgcn_exp2f(2.8853900817779268f * x));
}

#define MFMA16(A,B,C) __builtin_amdgcn_mfma_f32_16x16x32_bf16((A),(B),(C),0,0,0)
// packed 2xfp32 fma: element-wise IEEE fmaf, chains per element unchanged
#define FMA2(A,B,C) __builtin_elementwise_fma((A),(B),(C))

__global__ __launch_bounds__(TPB, 4) void lstm_kernel(
    const float* __restrict__ x, const float* __restrict__ ws,
    const float* __restrict__ W_init, const float* __restrict__ b_init,
    const float* __restrict__ b_out, float* __restrict__ out)
{
    __shared__ float          hxs [RPB][HID];    // 8 KB fp32 state
    __shared__ unsigned short hxhi[RPB][HXP2];   // 4.3 KB
    __shared__ unsigned short hxlo[RPB][HXP2];   // 4.3 KB

    const f32x4* W_effP4 = (const f32x4*)(ws);
    const f32x4* W_hhP4  = (const f32x4*)(ws + 65536);
    const float* b_all   = ws + 131072;
    const float* b2      = ws + 131584;
    const unsigned short* WoutHi = (const unsigned short*)(ws + 132096);
    const unsigned short* WoutLo = WoutHi + 8192;

    const int tid = threadIdx.x;
    const int h   = tid & 127;     // owned hidden/gate column
    const int rq  = tid >> 7;      // 0..1 -> row group of 8
    const int b0  = blockIdx.x * RPB;

    // ---- init GEMM (fp32): hx0 = x @ W_init^T + b_init (chain = R14) ----
    float cx[8];
    {
        float acc[8];
        const float bi = b_init[h];
        #pragma unroll
        for (int r = 0; r < 8; ++r) acc[r] = bi;
        for (int k0 = 0; k0 < INPUT; k0 += 4) {
            f32x4 wv = *(const f32x4*)&W_init[h*INPUT + k0];
            #pragma unroll
            for (int r = 0; r < 8; ++r) {
                const f32x4* xp = (const f32x4*)&x[(size_t)(b0 + rq*8 + r)*INPUT + k0];
                f32x4 xv = __builtin_nontemporal_load(xp);
                acc[r] = fmaf(xv.x, wv.x, acc[r]);
                acc[r] = fmaf(xv.y, wv.y, acc[r]);
                acc[r] = fmaf(xv.z, wv.z, acc[r]);
                acc[r] = fmaf(xv.w, wv.w, acc[r]);
            }
        }
        #pragma unroll
        for (int r = 0; r < 8; ++r) {
            int row = rq*8 + r;
            float v = acc[r];
            cx[r] = v;
            hxs[row][h] = v;
            unsigned short h0 = f2bf(v);
            hxhi[row][h] = h0;
            hxlo[row][h] = f2bf(v - bf2f(h0));
        }
    }
    __syncthreads();

    // ---- out-MFMA wave mapping (4 waves x one 16x16 C-tile each) ----
    const int w  = tid >> 6;        // wave 0..3
    const int l  = tid & 63;
    const int i  = l & 15;
    const int q  = l >> 4;
    const int jo = w*16 + i;        // out column
    const float boutj = b_out[jo];

    for (int t = 0; t < STEPS; ++t) {
        const f32x4* W4 = t ? W_effP4 : W_hhP4;
        const float* bb = t ? b_all   : b2;

        // ---- gates GEMM: v_pk_fma_f32 pairs (I,F) and (G,O).
        //      Per-element k-chains identical to R14 -> bit-identical numerics.
        f32x2 aIF[8], aGO[8];
        {
            const f32x2 bIF = {bb[h],       bb[128+h]};
            const f32x2 bGO = {bb[256+h],   bb[384+h]};
            #pragma unroll
            for (int r = 0; r < 8; ++r) { aIF[r] = bIF; aGO[r] = bGO; }
        }
        for (int k0 = 0; k0 < HID; k0 += 4) {
            f32x4 w0 = W4[(k0+0)*HID + h];
            f32x4 w1 = W4[(k0+1)*HID + h];
            f32x4 w2 = W4[(k0+2)*HID + h];
            f32x4 w3 = W4[(k0+3)*HID + h];
            f32x2 wIF0 = {w0.x, w0.y}, wGO0 = {w0.z, w0.w};
            f32x2 wIF1 = {w1.x, w1.y}, wGO1 = {w1.z, w1.w};
            f32x2 wIF2 = {w2.x, w2.y}, wGO2 = {w2.z, w2.w};
            f32x2 wIF3 = {w3.x, w3.y}, wGO3 = {w3.z, w3.w};
            #pragma unroll
            for (int r = 0; r < 8; ++r) {
                float4 hv = *(const float4*)&hxs[rq*8 + r][k0];
                f32x2 hx0 = {hv.x, hv.x};
                f32x2 hx1 = {hv.y, hv.y};
                f32x2 hx2 = {hv.z, hv.z};
                f32x2 hx3 = {hv.w, hv.w};
                aIF[r] = FMA2(hx0, wIF0, aIF[r]); aGO[r] = FMA2(hx0, wGO0, aGO[r]);
                aIF[r] = FMA2(hx1, wIF1, aIF[r]); aGO[r] = FMA2(hx1, wGO1, aGO[r]);
                aIF[r] = FMA2(hx2, wIF2, aIF[r]); aGO[r] = FMA2(hx2, wGO2, aGO[r]);
                aIF[r] = FMA2(hx3, wIF3, aIF[r]); aGO[r] = FMA2(hx3, wGO3, aGO[r]);
            }
        }
        __syncthreads();   // BAR1: all gates reads of hxs complete

        // ---- cell update (fp32, in-register cx; chain identical) ----
        #pragma unroll
        for (int r = 0; r < 8; ++r) {
            float ig = fast_sigmoid(aIF[r].x);
            float fg = fast_sigmoid(aIF[r].y);
            float gg = fast_tanh(aGO[r].x);
            float og = fast_sigmoid(aGO[r].y);
            float c  = fmaf(fg, cx[r], ig * gg);
            cx[r] = c;
            float hv = og * fast_tanh(c);
            int row = rq*8 + r;
            hxs[row][h] = hv;
            unsigned short h0 = f2bf(hv);
            hxhi[row][h] = h0;
            hxlo[row][h] = f2bf(hv - bf2f(h0));
        }
        __syncthreads();   // BAR2: new hx visible

        // ---- out GEMM via MFMA (unamplified error ~1e-5): 3-pass hi/lo ----
        {
            f32x4 oa = {boutj, boutj, boutj, boutj};
            #pragma unroll
            for (int kc = 0; kc < 4; ++kc) {
                const int ao = kc*32 + 8*q;
                short8 Ah = *(const short8*)&hxhi[i][ao];
                short8 Al = *(const short8*)&hxlo[i][ao];
                int oidx = ((kc*OUTW + jo) << 5) + (q << 3);
                short8 Bh = *(const short8*)&WoutHi[oidx];
                short8 Bl = *(const short8*)&WoutLo[oidx];
                oa = MFMA16(Ah, Bh, oa);
                oa = MFMA16(Ah, Bl, oa);
                oa = MFMA16(Al, Bh, oa);
            }
            #pragma unroll
            for (int r = 0; r < 4; ++r) {
                int row = 4*q + r;
                __builtin_nontemporal_store(oa[r],
                    &out[(size_t)(b0 + row)*(STEPS*OUTW) + t*OUTW + jo]);
            }
        }
        // no loop-end barrier: out(t)'s hxhi reads precede this thread's BAR1
        // of step t+1, and cell(t+1) writes follow it -> ordered.
    }
}

extern "C" void kernel_launch(void* const* d_in, const int* in_sizes, int n_in,
                              void* d_out, int out_size, void* d_ws, size_t ws_size,
                              hipStream_t stream)
{
    const float* x      = (const float*)d_in[0];
    const float* W_ih   = (const float*)d_in[1];
    const float* W_hh   = (const float*)d_in[2];
    const float* b_ih   = (const float*)d_in[3];
    const float* b_hh   = (const float*)d_in[4];
    const float* W_init = (const float*)d_in[5];
    const float* b_init = (const float*)d_in[6];
    const float* W_out  = (const float*)d_in[7];
    const float* b_out  = (const float*)d_in[8];
    float* out = (float*)d_out;
    float* ws  = (float*)d_ws;

    precompute_kernel<<<GATES, HID, 0, stream>>>(W_ih, W_hh, b_ih, b_hh, W_out, b_out, ws);
    lstm_kernel<<<B_TOTAL/RPB, TPB, 0, stream>>>(x, ws, W_init, b_init, b_out, out);
}